// Round 10
// baseline (1612.924 us; speedup 1.0000x reference)
//
#include <hip/hip_runtime.h>
#include <math.h>

#define N_NODES 50000
#define N_EDGES 800000
#define HC 64
#define HID 16
#define EDIM 16
#define NGRAPH 2000
#define BN_EPS 1e-5f
#define NBLK 1024
#define NTHR 256
#define NCHUNK 196                  // ceil(50000/256)
#define NTILE 1563                  // ceil(50000/32)
#define NGRP 6250                   // 50000 / 8 nodes per block-group
#define QKVS_NODES 32

// Fixed grid barrier: RELEASE arrival, RELAXED spin (no cache invalidation per
// poll — R6's bug), single ACQUIRE after exit. All NBLK blocks co-resident by
// __launch_bounds__(256,4) => 4 blocks/CU x 256 CUs = 1024.
__device__ __forceinline__ void grid_bar(int* cnt, int ph) {
    __syncthreads();
    if (threadIdx.x == 0) {
        __hip_atomic_fetch_add(cnt, 1, __ATOMIC_RELEASE, __HIP_MEMORY_SCOPE_AGENT);
        const int target = NBLK * ph;
        int guard = 0;
        while (__hip_atomic_load(cnt, __ATOMIC_RELAXED, __HIP_MEMORY_SCOPE_AGENT) < target) {
            __builtin_amdgcn_s_sleep(8);
            if (++guard > (1 << 22)) break;   // safety valve: fail loud, not hang
        }
        (void)__hip_atomic_load(cnt, __ATOMIC_ACQUIRE, __HIP_MEMORY_SCOPE_AGENT);
    }
    __syncthreads();
}

__device__ void qkvs_phase(const float* __restrict__ x,
                           const float* lWq, const float* lbq, const float* lWk, const float* lbk,
                           const float* lWv, const float* lbv, const float* lWs, const float* lbs,
                           const float* lWe,
                           float* Qo, float* KVo, float* So, float* qwe_buf, float* smem) {
    int tid = threadIdx.x;
    int sel = tid >> 6;
    int j = tid & 63;
    for (int tile = blockIdx.x; tile < NTILE; tile += NBLK) {
        int n0 = tile * QKVS_NODES;
        __syncthreads();   // protect smem from previous use
        for (int c = tid; c < QKVS_NODES * HC / 4; c += NTHR) {
            int row = c >> 4, col4 = c & 15;
            int n = n0 + row;
            float4 v = (n < N_NODES) ? ((const float4*)(x + (size_t)n * HC))[col4]
                                     : make_float4(0.f, 0.f, 0.f, 0.f);
            ((float4*)&smem[row * HC])[col4] = v;
        }
        __syncthreads();
        const float* W; const float* B; float* Out; int stride; int off;
        if (sel == 0)      { W = lWq; B = lbq; Out = Qo;  stride = HC;     off = 0;  }
        else if (sel == 1) { W = lWk; B = lbk; Out = KVo; stride = 2 * HC; off = 0;  }
        else if (sel == 2) { W = lWv; B = lbv; Out = KVo; stride = 2 * HC; off = HC; }
        else               { W = lWs; B = lbs; Out = So;  stride = HC;     off = 0;  }
        float bias = B[j];
        float acc[QKVS_NODES];
#pragma unroll
        for (int n = 0; n < QKVS_NODES; n++) acc[n] = bias;
        for (int i4 = 0; i4 < HC / 4; i4++) {
            float w0 = W[(i4 * 4 + 0) * HC + j];
            float w1 = W[(i4 * 4 + 1) * HC + j];
            float w2 = W[(i4 * 4 + 2) * HC + j];
            float w3 = W[(i4 * 4 + 3) * HC + j];
#pragma unroll
            for (int n = 0; n < QKVS_NODES; n++) {
                float4 xv = ((const float4*)&smem[n * HC])[i4];  // LDS broadcast
                acc[n] = fmaf(xv.x, w0, acc[n]);
                acc[n] = fmaf(xv.y, w1, acc[n]);
                acc[n] = fmaf(xv.z, w2, acc[n]);
                acc[n] = fmaf(xv.w, w3, acc[n]);
            }
        }
#pragma unroll
        for (int n = 0; n < QKVS_NODES; n++) {
            int node = n0 + n;
            if (node < N_NODES) Out[(size_t)node * stride + off + j] = acc[n];
        }
        // phase 2: qWe[node][h*16+jj] = sum_d Q[node][h*16+d] * We[jj][h*16+d]
        __syncthreads();
        if (sel == 0) {
#pragma unroll
            for (int n = 0; n < QKVS_NODES; n++) smem[n * HC + j] = acc[n];  // Q tile
        }
        __syncthreads();
        {
            int h2 = j >> 4, jj = j & 15;
            float4 wv0 = *(const float4*)(lWe + jj * HC + h2 * 16 + 0);
            float4 wv1 = *(const float4*)(lWe + jj * HC + h2 * 16 + 4);
            float4 wv2 = *(const float4*)(lWe + jj * HC + h2 * 16 + 8);
            float4 wv3 = *(const float4*)(lWe + jj * HC + h2 * 16 + 12);
#pragma unroll
            for (int n = 0; n < 8; n++) {
                int nn = sel * 8 + n;
                float4 q0 = *(const float4*)&smem[nn * HC + h2 * 16 + 0];
                float4 q1 = *(const float4*)&smem[nn * HC + h2 * 16 + 4];
                float4 q2 = *(const float4*)&smem[nn * HC + h2 * 16 + 8];
                float4 q3 = *(const float4*)&smem[nn * HC + h2 * 16 + 12];
                float s = q0.x * wv0.x + q0.y * wv0.y + q0.z * wv0.z + q0.w * wv0.w
                        + q1.x * wv1.x + q1.y * wv1.y + q1.z * wv1.z + q1.w * wv1.w
                        + q2.x * wv2.x + q2.y * wv2.y + q2.z * wv2.z + q2.w * wv2.w
                        + q3.x * wv3.x + q3.y * wv3.y + q3.z * wv3.z + q3.w * wv3.w;
                int node = n0 + nn;
                if (node < N_NODES) qwe_buf[(size_t)node * HC + j] = s;
            }
        }
    }
}

__device__ void attn_phase(const float* __restrict__ Qf, const float* __restrict__ Qwe,
                           const float* __restrict__ KV, const float* __restrict__ Sf,
                           const int* __restrict__ row_ptr, const int* __restrict__ src_s,
                           const float* __restrict__ ea_s, const float* __restrict__ We,
                           const float* lg, const float* lb, const float* lm, const float* lv,
                           float* __restrict__ x_out, float* smem) {
    int tid = threadIdx.x;
    float* we_s = smem;   // 4 KB
    __syncthreads();
    for (int c = tid; c < EDIM * HC / 4; c += NTHR)
        ((float4*)we_s)[c] = ((const float4*)We)[c];
    __syncthreads();

    int lane = tid & 63;
    int wave = tid >> 6;
    int half = lane >> 5;
    int sub = (lane >> 4) & 1;
    int pos = lane & 15;
    int h = pos >> 2;

    for (int grp = blockIdx.x; grp < NGRP; grp += NBLK) {
        int node = grp * 8 + wave * 2 + half;
        int rbeg = row_ptr[node], rend = row_ptr[node + 1];
        float4 q4 = ((const float4*)(Qf + (size_t)node * HC))[pos];
        float4 qwe = ((const float4*)(Qwe + (size_t)node * HC))[pos];

        float m = -1e30f, den = 0.f;
        float4 acc = make_float4(0.f, 0.f, 0.f, 0.f);
        float4 aea = make_float4(0.f, 0.f, 0.f, 0.f);

        auto proc = [&](float4 k4, float4 ea4) -> float {
            float dot = q4.x * k4.x + q4.y * k4.y + q4.z * k4.z + q4.w * k4.w
                      + qwe.x * ea4.x + qwe.y * ea4.y + qwe.z * ea4.z + qwe.w * ea4.w;
            dot += __shfl_xor(dot, 1);
            dot += __shfl_xor(dot, 2);
            float logit = dot * 0.25f;
            float mn = fmaxf(m, logit);
            float corr = __expf(m - mn);
            float p = __expf(logit - mn);
            den = den * corr + p;
            acc.x *= corr; acc.y *= corr; acc.z *= corr; acc.w *= corr;
            aea.x *= corr; aea.y *= corr; aea.z *= corr; aea.w *= corr;
            m = mn;
            return p;
        };

        int j = rbeg + sub;
        for (; j + 2 < rend; j += 4) {
            int s0 = src_s[j];
            int s1 = src_s[j + 2];
            const float4* kv0 = (const float4*)(KV + (size_t)s0 * 2 * HC);
            const float4* kv1 = (const float4*)(KV + (size_t)s1 * 2 * HC);
            float4 k0 = kv0[pos], v0 = kv0[16 + pos];
            float4 k1 = kv1[pos], v1 = kv1[16 + pos];
            float4 ea0 = ((const float4*)(ea_s + (size_t)j * EDIM))[pos & 3];
            float4 ea1 = ((const float4*)(ea_s + (size_t)(j + 2) * EDIM))[pos & 3];
            float p0 = proc(k0, ea0);
            acc.x = fmaf(p0, v0.x, acc.x); acc.y = fmaf(p0, v0.y, acc.y);
            acc.z = fmaf(p0, v0.z, acc.z); acc.w = fmaf(p0, v0.w, acc.w);
            aea.x = fmaf(p0, ea0.x, aea.x); aea.y = fmaf(p0, ea0.y, aea.y);
            aea.z = fmaf(p0, ea0.z, aea.z); aea.w = fmaf(p0, ea0.w, aea.w);
            float p1 = proc(k1, ea1);
            acc.x = fmaf(p1, v1.x, acc.x); acc.y = fmaf(p1, v1.y, acc.y);
            acc.z = fmaf(p1, v1.z, acc.z); acc.w = fmaf(p1, v1.w, acc.w);
            aea.x = fmaf(p1, ea1.x, aea.x); aea.y = fmaf(p1, ea1.y, aea.y);
            aea.z = fmaf(p1, ea1.z, aea.z); aea.w = fmaf(p1, ea1.w, aea.w);
        }
        if (j < rend) {
            int s0 = src_s[j];
            const float4* kv0 = (const float4*)(KV + (size_t)s0 * 2 * HC);
            float4 k0 = kv0[pos], v0 = kv0[16 + pos];
            float4 ea0 = ((const float4*)(ea_s + (size_t)j * EDIM))[pos & 3];
            float p0 = proc(k0, ea0);
            acc.x = fmaf(p0, v0.x, acc.x); acc.y = fmaf(p0, v0.y, acc.y);
            acc.z = fmaf(p0, v0.z, acc.z); acc.w = fmaf(p0, v0.w, acc.w);
            aea.x = fmaf(p0, ea0.x, aea.x); aea.y = fmaf(p0, ea0.y, aea.y);
            aea.z = fmaf(p0, ea0.z, aea.z); aea.w = fmaf(p0, ea0.w, aea.w);
        }

        // merge 2 sub-streams (within the 32-lane half)
        {
            float m2 = __shfl_xor(m, 16);
            float d2 = __shfl_xor(den, 16);
            float ax = __shfl_xor(acc.x, 16), ay = __shfl_xor(acc.y, 16);
            float az = __shfl_xor(acc.z, 16), aw = __shfl_xor(acc.w, 16);
            float bx = __shfl_xor(aea.x, 16), by = __shfl_xor(aea.y, 16);
            float bz = __shfl_xor(aea.z, 16), bw = __shfl_xor(aea.w, 16);
            float mn = fmaxf(m, m2);
            float c1 = __expf(m - mn), c2 = __expf(m2 - mn);
            den = den * c1 + d2 * c2;
            acc.x = acc.x * c1 + ax * c2; acc.y = acc.y * c1 + ay * c2;
            acc.z = acc.z * c1 + az * c2; acc.w = acc.w * c1 + aw * c2;
            aea.x = aea.x * c1 + bx * c2; aea.y = aea.y * c1 + by * c2;
            aea.z = aea.z * c1 + bz * c2; aea.w = aea.w * c1 + bw * c2;
            m = mn;
        }

        float4 e4 = make_float4(0.f, 0.f, 0.f, 0.f);
#pragma unroll
        for (int jg = 0; jg < 4; jg++) {
            int sl = (lane & 32) | (h * 4 + jg);
            float a0 = __shfl(aea.x, sl), a1 = __shfl(aea.y, sl);
            float a2 = __shfl(aea.z, sl), a3 = __shfl(aea.w, sl);
            float4 w0 = *(const float4*)(we_s + (jg * 4 + 0) * HC + pos * 4);
            float4 w1 = *(const float4*)(we_s + (jg * 4 + 1) * HC + pos * 4);
            float4 w2 = *(const float4*)(we_s + (jg * 4 + 2) * HC + pos * 4);
            float4 w3 = *(const float4*)(we_s + (jg * 4 + 3) * HC + pos * 4);
            e4.x += a0 * w0.x + a1 * w1.x + a2 * w2.x + a3 * w3.x;
            e4.y += a0 * w0.y + a1 * w1.y + a2 * w2.y + a3 * w3.y;
            e4.z += a0 * w0.z + a1 * w1.z + a2 * w2.z + a3 * w3.z;
            e4.w += a0 * w0.w + a1 * w1.w + a2 * w2.w + a3 * w3.w;
        }

        float inv = (rend > rbeg) ? 1.f / den : 0.f;
        float4 sk = ((const float4*)(Sf + (size_t)node * HC))[pos];
        float4 o = make_float4((acc.x + e4.x) * inv + sk.x, (acc.y + e4.y) * inv + sk.y,
                               (acc.z + e4.z) * inv + sk.z, (acc.w + e4.w) * inv + sk.w);
        float4 g4 = ((const float4*)lg)[pos];
        float4 b4 = ((const float4*)lb)[pos];
        float4 m4 = ((const float4*)lm)[pos];
        float4 vv4 = ((const float4*)lv)[pos];
        o.x = fmaxf((o.x - m4.x) * rsqrtf(vv4.x + BN_EPS) * g4.x + b4.x, 0.f);
        o.y = fmaxf((o.y - m4.y) * rsqrtf(vv4.y + BN_EPS) * g4.y + b4.y, 0.f);
        o.z = fmaxf((o.z - m4.z) * rsqrtf(vv4.z + BN_EPS) * g4.z + b4.z, 0.f);
        o.w = fmaxf((o.w - m4.w) * rsqrtf(vv4.w + BN_EPS) * g4.w + b4.w, 0.f);
        if (sub == 0) ((float4*)(x_out + (size_t)node * HC))[pos] = o;
    }
}

__global__ __launch_bounds__(256, 4) void fused_gnn(
    const float* __restrict__ x0, const int* __restrict__ ei,
    const float* __restrict__ edge_attr, const int* __restrict__ batch,
    const float* __restrict__ Wq, const float* __restrict__ bq,
    const float* __restrict__ Wk, const float* __restrict__ bk,
    const float* __restrict__ Wv, const float* __restrict__ bv,
    const float* __restrict__ WeL, const float* __restrict__ Wsk, const float* __restrict__ bsk,
    const float* __restrict__ bng, const float* __restrict__ bnb,
    const float* __restrict__ bnm, const float* __restrict__ bnv,
    const float* __restrict__ fc1_w, const float* __restrict__ fc1_b,
    const float* __restrict__ fc2_w, const float* __restrict__ fc2_b,
    float* __restrict__ xA, float* __restrict__ xB,
    float* __restrict__ Qb, float* __restrict__ Sb, float* __restrict__ KVb,
    float* __restrict__ qweb,
    int* __restrict__ bar, int* __restrict__ deg,
    int* __restrict__ row_ptr, int* __restrict__ nxt, int* __restrict__ bsum,
    int2* __restrict__ ep_s, int* __restrict__ src_s, float* __restrict__ ea_s,
    float* __restrict__ out) {
    __shared__ float smem[QKVS_NODES * HC];   // 8 KB, reused by all phases
    int tid = threadIdx.x;
    int bid = blockIdx.x;
    int ph = 0;

    // P1: count in-degree (deg zeroed by host-side memset together with bar)
    for (int e = bid * NTHR + tid; e < N_EDGES; e += NBLK * NTHR)
        atomicAdd(&deg[ei[N_EDGES + e]], 1);
    grid_bar(bar, ++ph);

    // P2: per-chunk sums
    if (bid < NCHUNK) {
        int* s = (int*)smem;
        int i = bid * NTHR + tid;
        s[tid] = (i < N_NODES) ? deg[i] : 0;
        __syncthreads();
        for (int d = 128; d > 0; d >>= 1) {
            if (tid < d) s[tid] += s[tid + d];
            __syncthreads();
        }
        if (tid == 0) bsum[bid] = s[0];
    }
    grid_bar(bar, ++ph);

    // P3: fused chunk-prefix + per-chunk exclusive scan -> row_ptr / nxt
    if (bid < NCHUNK) {
        int* s = (int*)smem;
        __shared__ int boff_s;
        s[tid] = (tid < bid && tid < NCHUNK) ? bsum[tid] : 0;
        __syncthreads();
        for (int d = 128; d > 0; d >>= 1) {
            if (tid < d) s[tid] += s[tid + d];
            __syncthreads();
        }
        if (tid == 0) boff_s = s[0];
        __syncthreads();
        int boff = boff_s;
        __syncthreads();
        int i = bid * NTHR + tid;
        int v = (i < N_NODES) ? deg[i] : 0;
        s[tid] = v;
        __syncthreads();
        for (int d = 1; d < 256; d <<= 1) {
            int t = (tid >= d) ? s[tid - d] : 0;
            __syncthreads();
            s[tid] += t;
            __syncthreads();
        }
        int excl = s[tid] - v + boff;
        if (i < N_NODES) { row_ptr[i] = excl; nxt[i] = excl; }
        if (i == 0) row_ptr[N_NODES] = N_EDGES;
    }
    grid_bar(bar, ++ph);

    // P4: scatter (src,eid) into CSR slots — 8 B random writes
    for (int e = bid * NTHR + tid; e < N_EDGES; e += NBLK * NTHR) {
        int d = ei[N_EDGES + e];
        int p = atomicAdd(&nxt[d], 1);
        ep_s[p] = make_int2(ei[e], e);
    }
    grid_bar(bar, ++ph);

    // P5a: permute edge_attr into CSR order + emit compact src_s (coalesced writes)
    for (int t = bid * NTHR + tid; t < N_EDGES * 4; t += NBLK * NTHR) {
        int p = t >> 2, c = t & 3;
        int2 pe = ep_s[p];
        if (c == 0) src_s[p] = pe.x;
        ((float4*)ea_s)[p * 4 + c] = ((const float4*)edge_attr)[pe.y * 4 + c];
    }
    // P5b: qkvs layer 0 (independent of CSR — needs only x0)
    qkvs_phase(x0, Wq, bq, Wk, bk, Wv, bv, Wsk, bsk, WeL, Qb, KVb, Sb, qweb, smem);
    grid_bar(bar, ++ph);

    // layer 0 attn
    attn_phase(Qb, qweb, KVb, Sb, row_ptr, src_s, ea_s, WeL,
               bng, bnb, bnm, bnv, xA, smem);
    grid_bar(bar, ++ph);

    // layer 1
    qkvs_phase(xA, Wq + HC * HC, bq + HC, Wk + HC * HC, bk + HC,
               Wv + HC * HC, bv + HC, Wsk + HC * HC, bsk + HC,
               WeL + EDIM * HC, Qb, KVb, Sb, qweb, smem);
    grid_bar(bar, ++ph);
    attn_phase(Qb, qweb, KVb, Sb, row_ptr, src_s, ea_s, WeL + EDIM * HC,
               bng + HC, bnb + HC, bnm + HC, bnv + HC, xB, smem);
    grid_bar(bar, ++ph);

    // layer 2
    qkvs_phase(xB, Wq + 2 * HC * HC, bq + 2 * HC, Wk + 2 * HC * HC, bk + 2 * HC,
               Wv + 2 * HC * HC, bv + 2 * HC, Wsk + 2 * HC * HC, bsk + 2 * HC,
               WeL + 2 * EDIM * HC, Qb, KVb, Sb, qweb, smem);
    grid_bar(bar, ++ph);
    attn_phase(Qb, qweb, KVb, Sb, row_ptr, src_s, ea_s, WeL + 2 * EDIM * HC,
               bng + 2 * HC, bnb + 2 * HC, bnm + 2 * HC, bnv + 2 * HC, xA, smem);
    grid_bar(bar, ++ph);

    // pool + MLP head: one wave per graph, 4 graphs per block
    for (int pg = bid; pg < NGRAPH / 4; pg += NBLK) {
        __syncthreads();
        float* ps = smem;
        int q = tid >> 6;
        int lane = tid & 63;
        int g = pg * 4 + q;
        int lo = 0, hi = N_NODES;
        while (lo < hi) { int mid = (lo + hi) >> 1; if (batch[mid] < g) lo = mid + 1; else hi = mid; }
        int beg = lo;
        lo = 0; hi = N_NODES;
        while (lo < hi) { int mid = (lo + hi) >> 1; if (batch[mid] < g + 1) lo = mid + 1; else hi = mid; }
        int end = lo;
        float s = 0.f;
        for (int i = beg; i < end; i++) s += xA[(size_t)i * HC + lane];
        float invn = (end > beg) ? 1.f / (float)(end - beg) : 1.f;
        ps[q * HC + lane] = s * invn;
        __syncthreads();
        float o = 0.f;
        if (lane < HID) {
            float a = fc1_b[lane];
#pragma unroll
            for (int i = 0; i < HC; i++) a = fmaf(ps[q * HC + i], fc1_w[i * HID + lane], a);
            o = fmaxf(a, 0.f) * fc2_w[lane];
        }
        o += __shfl_xor(o, 1);
        o += __shfl_xor(o, 2);
        o += __shfl_xor(o, 4);
        o += __shfl_xor(o, 8);
        if (lane == 0) out[g] = o + fc2_b[0];
    }
}

extern "C" void kernel_launch(void* const* d_in, const int* in_sizes, int n_in,
                              void* d_out, int out_size, void* d_ws, size_t ws_size,
                              hipStream_t stream) {
    const float* x         = (const float*)d_in[0];
    const int*   ei        = (const int*)d_in[1];
    const float* edge_attr = (const float*)d_in[2];
    const int*   batch     = (const int*)d_in[3];
    const float* Wq = (const float*)d_in[4];  const float* bq = (const float*)d_in[5];
    const float* Wk = (const float*)d_in[6];  const float* bk = (const float*)d_in[7];
    const float* Wv = (const float*)d_in[8];  const float* bv = (const float*)d_in[9];
    const float* We = (const float*)d_in[10];
    const float* Ws = (const float*)d_in[11]; const float* bs = (const float*)d_in[12];
    const float* bng = (const float*)d_in[13]; const float* bnb = (const float*)d_in[14];
    const float* bnm = (const float*)d_in[15]; const float* bnv = (const float*)d_in[16];
    const float* fc1_w = (const float*)d_in[17]; const float* fc1_b = (const float*)d_in[18];
    const float* fc2_w = (const float*)d_in[19]; const float* fc2_b = (const float*)d_in[20];
    float* out = (float*)d_out;

    char* wp = (char*)d_ws;
    auto alloc = [&](size_t b) { void* p = (void*)wp; wp += (b + 255) & ~(size_t)255; return p; };
    int*   bar     = (int*)alloc((size_t)256);                    // must precede deg (one memset)
    int*   deg     = (int*)alloc((size_t)N_NODES * 4);
    int*   row_ptr = (int*)alloc((size_t)(N_NODES + 1) * 4);
    int*   nxt     = (int*)alloc((size_t)N_NODES * 4);
    int*   bsum    = (int*)alloc((size_t)256 * 4);
    int2*  ep_s    = (int2*)alloc((size_t)N_EDGES * 8);
    int*   src_s   = (int*)alloc((size_t)N_EDGES * 4);
    float* ea_s    = (float*)alloc((size_t)N_EDGES * EDIM * 4);
    float* xA      = (float*)alloc((size_t)N_NODES * HC * 4);
    float* xB      = (float*)alloc((size_t)N_NODES * HC * 4);
    float* Qb      = (float*)alloc((size_t)N_NODES * HC * 4);
    float* Sb      = (float*)alloc((size_t)N_NODES * HC * 4);
    float* KV      = (float*)alloc((size_t)N_NODES * 2 * HC * 4);
    float* qweb    = (float*)alloc((size_t)N_NODES * HC * 4);

    // one memset covers bar (256 B) + deg (200000 B), contiguous
    (void)hipMemsetAsync(bar, 0, 256 + (size_t)N_NODES * 4, stream);

    fused_gnn<<<NBLK, NTHR, 0, stream>>>(
        x, ei, edge_attr, batch,
        Wq, bq, Wk, bk, Wv, bv, We, Ws, bs,
        bng, bnb, bnm, bnv, fc1_w, fc1_b, fc2_w, fc2_b,
        xA, xB, Qb, Sb, KV, qweb,
        bar, deg, row_ptr, nxt, bsum, ep_s, src_s, ea_s, out);
}

// Round 11
// 612.454 us; speedup vs baseline: 2.6335x; 2.6335x over previous
//
#include <hip/hip_runtime.h>
#include <math.h>

#define N_NODES 50000
#define N_EDGES 800000
#define HC 64
#define HID 16
#define EDIM 16
#define NGRAPH 2000
#define BN_EPS 1e-5f
#define QKVS_NODES 32
#define SCAN_NBLK ((N_NODES + 255) / 256)   // 196
#define CD_BLOCKS ((N_EDGES + 255) / 256)   // 3125
#define QKVS_TILES ((N_NODES + QKVS_NODES - 1) / QKVS_NODES)  // 1563

// ---------- qkvs tile body (shared by merged and standalone kernels) ----------
__device__ __forceinline__ void qkvs_tile(
    int tile, const float* __restrict__ x,
    const float* lWq, const float* lbq, const float* lWk, const float* lbk,
    const float* lWv, const float* lbv, const float* lWs, const float* lbs,
    const float* lWe,
    float* Qo, float* KVo, float* So, float* qwe_buf, float* xs) {
    int tid = threadIdx.x;
    int n0 = tile * QKVS_NODES;
    for (int c = tid; c < QKVS_NODES * HC / 4; c += 256) {
        int row = c >> 4, col4 = c & 15;
        int n = n0 + row;
        float4 v = (n < N_NODES) ? ((const float4*)(x + (size_t)n * HC))[col4]
                                 : make_float4(0.f, 0.f, 0.f, 0.f);
        ((float4*)&xs[row * HC])[col4] = v;
    }
    __syncthreads();
    int sel = tid >> 6;
    int j = tid & 63;
    const float* W; const float* B; float* Out; int stride; int off;
    if (sel == 0)      { W = lWq; B = lbq; Out = Qo;  stride = HC;     off = 0;  }
    else if (sel == 1) { W = lWk; B = lbk; Out = KVo; stride = 2 * HC; off = 0;  }
    else if (sel == 2) { W = lWv; B = lbv; Out = KVo; stride = 2 * HC; off = HC; }
    else               { W = lWs; B = lbs; Out = So;  stride = HC;     off = 0;  }
    float bias = B[j];
    float acc[QKVS_NODES];
#pragma unroll
    for (int n = 0; n < QKVS_NODES; n++) acc[n] = bias;
    for (int i4 = 0; i4 < HC / 4; i4++) {
        float w0 = W[(i4 * 4 + 0) * HC + j];
        float w1 = W[(i4 * 4 + 1) * HC + j];
        float w2 = W[(i4 * 4 + 2) * HC + j];
        float w3 = W[(i4 * 4 + 3) * HC + j];
#pragma unroll
        for (int n = 0; n < QKVS_NODES; n++) {
            float4 xv = ((const float4*)&xs[n * HC])[i4];  // LDS broadcast
            acc[n] = fmaf(xv.x, w0, acc[n]);
            acc[n] = fmaf(xv.y, w1, acc[n]);
            acc[n] = fmaf(xv.z, w2, acc[n]);
            acc[n] = fmaf(xv.w, w3, acc[n]);
        }
    }
#pragma unroll
    for (int n = 0; n < QKVS_NODES; n++) {
        int node = n0 + n;
        if (node < N_NODES) Out[(size_t)node * stride + off + j] = acc[n];
    }
    // phase 2: qWe[node][h*16+jj] = sum_d Q[node][h*16+d] * We[jj][h*16+d]
    __syncthreads();
    if (sel == 0) {
#pragma unroll
        for (int n = 0; n < QKVS_NODES; n++) xs[n * HC + j] = acc[n];  // Q tile
    }
    __syncthreads();
    {
        int h2 = j >> 4, jj = j & 15;
        float4 wv0 = *(const float4*)(lWe + jj * HC + h2 * 16 + 0);
        float4 wv1 = *(const float4*)(lWe + jj * HC + h2 * 16 + 4);
        float4 wv2 = *(const float4*)(lWe + jj * HC + h2 * 16 + 8);
        float4 wv3 = *(const float4*)(lWe + jj * HC + h2 * 16 + 12);
#pragma unroll
        for (int n = 0; n < 8; n++) {
            int nn = sel * 8 + n;
            float4 q0 = *(const float4*)&xs[nn * HC + h2 * 16 + 0];
            float4 q1 = *(const float4*)&xs[nn * HC + h2 * 16 + 4];
            float4 q2 = *(const float4*)&xs[nn * HC + h2 * 16 + 8];
            float4 q3 = *(const float4*)&xs[nn * HC + h2 * 16 + 12];
            float s = q0.x * wv0.x + q0.y * wv0.y + q0.z * wv0.z + q0.w * wv0.w
                    + q1.x * wv1.x + q1.y * wv1.y + q1.z * wv1.z + q1.w * wv1.w
                    + q2.x * wv2.x + q2.y * wv2.y + q2.z * wv2.z + q2.w * wv2.w
                    + q3.x * wv3.x + q3.y * wv3.y + q3.z * wv3.z + q3.w * wv3.w;
            int node = n0 + nn;
            if (node < N_NODES) qwe_buf[(size_t)node * HC + j] = s;
        }
    }
}

// ---------- merged: count_deg (atomic histogram) || qkvs layer 0 ----------
__global__ __launch_bounds__(256) void count_qkvs0(
    const int* __restrict__ ei, int* __restrict__ deg,
    const float* __restrict__ x,
    const float* __restrict__ Wq, const float* __restrict__ bq,
    const float* __restrict__ Wk, const float* __restrict__ bk,
    const float* __restrict__ Wv, const float* __restrict__ bv,
    const float* __restrict__ Ws, const float* __restrict__ bs,
    const float* __restrict__ We,
    float* __restrict__ Qo, float* __restrict__ KVo, float* __restrict__ So,
    float* __restrict__ qwe_buf) {
    __shared__ float xs[QKVS_NODES * HC];   // 8 KB (unused by count blocks)
    if (blockIdx.x < CD_BLOCKS) {
        int e = blockIdx.x * 256 + threadIdx.x;
        if (e < N_EDGES) atomicAdd(&deg[ei[N_EDGES + e]], 1);
    } else {
        qkvs_tile(blockIdx.x - CD_BLOCKS, x, Wq, bq, Wk, bk, Wv, bv, Ws, bs, We,
                  Qo, KVo, So, qwe_buf, xs);
    }
}

// ---------- standalone qkvs (layers 1,2) ----------
__global__ __launch_bounds__(256) void qkvs_kernel(
    const float* __restrict__ x,
    const float* __restrict__ Wq, const float* __restrict__ bq,
    const float* __restrict__ Wk, const float* __restrict__ bk,
    const float* __restrict__ Wv, const float* __restrict__ bv,
    const float* __restrict__ Ws, const float* __restrict__ bs,
    const float* __restrict__ We,
    float* __restrict__ Qo, float* __restrict__ KVo, float* __restrict__ So,
    float* __restrict__ qwe_buf) {
    __shared__ float xs[QKVS_NODES * HC];
    qkvs_tile(blockIdx.x, x, Wq, bq, Wk, bk, Wv, bv, Ws, bs, We,
              Qo, KVo, So, qwe_buf, xs);
}

// ---------- scans ----------
__global__ __launch_bounds__(256) void scan1(const int* __restrict__ deg, int* __restrict__ bsum) {
    __shared__ int s[256];
    int tid = threadIdx.x;
    int i = blockIdx.x * 256 + tid;
    s[tid] = (i < N_NODES) ? deg[i] : 0;
    __syncthreads();
    for (int d = 128; d > 0; d >>= 1) {
        if (tid < d) s[tid] += s[tid + d];
        __syncthreads();
    }
    if (tid == 0) bsum[blockIdx.x] = s[0];
}

__global__ __launch_bounds__(256) void scan3(const int* __restrict__ deg, const int* __restrict__ bsum,
                                             int* __restrict__ row_ptr, int* __restrict__ nxt) {
    __shared__ int s[256];
    __shared__ int boff_s;
    int tid = threadIdx.x;
    s[tid] = (tid < blockIdx.x && tid < SCAN_NBLK) ? bsum[tid] : 0;
    __syncthreads();
    for (int d = 128; d > 0; d >>= 1) {
        if (tid < d) s[tid] += s[tid + d];
        __syncthreads();
    }
    if (tid == 0) boff_s = s[0];
    __syncthreads();
    int boff = boff_s;
    __syncthreads();
    int i = blockIdx.x * 256 + tid;
    int v = (i < N_NODES) ? deg[i] : 0;
    s[tid] = v;
    __syncthreads();
    for (int d = 1; d < 256; d <<= 1) {
        int t = (tid >= d) ? s[tid - d] : 0;
        __syncthreads();
        s[tid] += t;
        __syncthreads();
    }
    int excl = s[tid] - v + boff;
    if (i < N_NODES) { row_ptr[i] = excl; nxt[i] = excl; }
    if (i == 0) row_ptr[N_NODES] = N_EDGES;
}

// ---------- scatter (src,eid) pairs — 8 B random writes only ----------
__global__ void scatter_eid(const int* __restrict__ ei, int* __restrict__ next_ptr,
                            int2* __restrict__ ep_s) {
    int e = blockIdx.x * blockDim.x + threadIdx.x;
    if (e < N_EDGES) {
        int d = ei[N_EDGES + e];
        int p = atomicAdd(&next_ptr[d], 1);
        ep_s[p] = make_int2(ei[e], e);
    }
}

// ---------- permute edge_attr into CSR order + emit compact src_s ----------
__global__ void permute_ea(const int2* __restrict__ ep_s, const float* __restrict__ edge_attr,
                           float* __restrict__ ea_s, int* __restrict__ src_s) {
    int t = blockIdx.x * blockDim.x + threadIdx.x;
    if (t >= N_EDGES * 4) return;
    int p = t >> 2, c = t & 3;
    int2 pe = ep_s[p];
    if (c == 0) src_s[p] = pe.x;
    ((float4*)ea_s)[p * 4 + c] = ((const float4*)edge_attr)[pe.y * 4 + c];
}

// ---------- attention + skip + BN + ReLU: two nodes/wave, 3-edge unrolled ----------
__global__ __launch_bounds__(256) void attn_kernel(
    const float* __restrict__ Qf, const float* __restrict__ Qwe,
    const float* __restrict__ KV, const float* __restrict__ Sf,
    const int* __restrict__ row_ptr, const int* __restrict__ src_s,
    const float* __restrict__ ea_s, const float* __restrict__ We,
    const float* __restrict__ bng, const float* __restrict__ bnb,
    const float* __restrict__ bnm, const float* __restrict__ bnv,
    float* __restrict__ x_out) {
    __shared__ float we_s[EDIM * HC];  // 4 KB
    int tid = threadIdx.x;
    for (int c = tid; c < EDIM * HC / 4; c += 256)
        ((float4*)we_s)[c] = ((const float4*)We)[c];
    __syncthreads();

    int lane = tid & 63;
    int wave = tid >> 6;
    int half = lane >> 5;
    int node = blockIdx.x * 8 + wave * 2 + half;  // 6250 blocks * 8 = 50000
    int sub = (lane >> 4) & 1;
    int pos = lane & 15;
    int h = pos >> 2;
    int rbeg = row_ptr[node], rend = row_ptr[node + 1];

    float4 q4 = ((const float4*)(Qf + (size_t)node * HC))[pos];
    float4 qwe = ((const float4*)(Qwe + (size_t)node * HC))[pos];

    float m = -1e30f, den = 0.f;
    float4 acc = make_float4(0.f, 0.f, 0.f, 0.f);
    float4 aea = make_float4(0.f, 0.f, 0.f, 0.f);

    auto proc = [&](float4 k4, float4 ea4) -> float {
        float dot = q4.x * k4.x + q4.y * k4.y + q4.z * k4.z + q4.w * k4.w
                  + qwe.x * ea4.x + qwe.y * ea4.y + qwe.z * ea4.z + qwe.w * ea4.w;
        dot += __shfl_xor(dot, 1);
        dot += __shfl_xor(dot, 2);
        float logit = dot * 0.25f;
        float mn = fmaxf(m, logit);
        float corr = __expf(m - mn);
        float p = __expf(logit - mn);
        den = den * corr + p;
        acc.x *= corr; acc.y *= corr; acc.z *= corr; acc.w *= corr;
        aea.x *= corr; aea.y *= corr; aea.z *= corr; aea.w *= corr;
        m = mn;
        return p;
    };

    int j = rbeg + sub;
    for (; j + 4 < rend; j += 6) {
        int s0 = src_s[j];
        int s1 = src_s[j + 2];
        int s2 = src_s[j + 4];
        const float4* kv0 = (const float4*)(KV + (size_t)s0 * 2 * HC);
        const float4* kv1 = (const float4*)(KV + (size_t)s1 * 2 * HC);
        const float4* kv2 = (const float4*)(KV + (size_t)s2 * 2 * HC);
        float4 k0 = kv0[pos], v0 = kv0[16 + pos];
        float4 k1 = kv1[pos], v1 = kv1[16 + pos];
        float4 k2 = kv2[pos], v2 = kv2[16 + pos];
        float4 ea0 = ((const float4*)(ea_s + (size_t)j * EDIM))[pos & 3];
        float4 ea1 = ((const float4*)(ea_s + (size_t)(j + 2) * EDIM))[pos & 3];
        float4 ea2 = ((const float4*)(ea_s + (size_t)(j + 4) * EDIM))[pos & 3];
        float p0 = proc(k0, ea0);
        acc.x = fmaf(p0, v0.x, acc.x); acc.y = fmaf(p0, v0.y, acc.y);
        acc.z = fmaf(p0, v0.z, acc.z); acc.w = fmaf(p0, v0.w, acc.w);
        aea.x = fmaf(p0, ea0.x, aea.x); aea.y = fmaf(p0, ea0.y, aea.y);
        aea.z = fmaf(p0, ea0.z, aea.z); aea.w = fmaf(p0, ea0.w, aea.w);
        float p1 = proc(k1, ea1);
        acc.x = fmaf(p1, v1.x, acc.x); acc.y = fmaf(p1, v1.y, acc.y);
        acc.z = fmaf(p1, v1.z, acc.z); acc.w = fmaf(p1, v1.w, acc.w);
        aea.x = fmaf(p1, ea1.x, aea.x); aea.y = fmaf(p1, ea1.y, aea.y);
        aea.z = fmaf(p1, ea1.z, aea.z); aea.w = fmaf(p1, ea1.w, aea.w);
        float p2 = proc(k2, ea2);
        acc.x = fmaf(p2, v2.x, acc.x); acc.y = fmaf(p2, v2.y, acc.y);
        acc.z = fmaf(p2, v2.z, acc.z); acc.w = fmaf(p2, v2.w, acc.w);
        aea.x = fmaf(p2, ea2.x, aea.x); aea.y = fmaf(p2, ea2.y, aea.y);
        aea.z = fmaf(p2, ea2.z, aea.z); aea.w = fmaf(p2, ea2.w, aea.w);
    }
    for (; j < rend; j += 2) {
        int s0 = src_s[j];
        const float4* kv0 = (const float4*)(KV + (size_t)s0 * 2 * HC);
        float4 k0 = kv0[pos], v0 = kv0[16 + pos];
        float4 ea0 = ((const float4*)(ea_s + (size_t)j * EDIM))[pos & 3];
        float p0 = proc(k0, ea0);
        acc.x = fmaf(p0, v0.x, acc.x); acc.y = fmaf(p0, v0.y, acc.y);
        acc.z = fmaf(p0, v0.z, acc.z); acc.w = fmaf(p0, v0.w, acc.w);
        aea.x = fmaf(p0, ea0.x, aea.x); aea.y = fmaf(p0, ea0.y, aea.y);
        aea.z = fmaf(p0, ea0.z, aea.z); aea.w = fmaf(p0, ea0.w, aea.w);
    }

    // merge 2 sub-streams (within the 32-lane half)
    {
        float m2 = __shfl_xor(m, 16);
        float d2 = __shfl_xor(den, 16);
        float ax = __shfl_xor(acc.x, 16), ay = __shfl_xor(acc.y, 16);
        float az = __shfl_xor(acc.z, 16), aw = __shfl_xor(acc.w, 16);
        float bx = __shfl_xor(aea.x, 16), by = __shfl_xor(aea.y, 16);
        float bz = __shfl_xor(aea.z, 16), bw = __shfl_xor(aea.w, 16);
        float mn = fmaxf(m, m2);
        float c1 = __expf(m - mn), c2 = __expf(m2 - mn);
        den = den * c1 + d2 * c2;
        acc.x = acc.x * c1 + ax * c2; acc.y = acc.y * c1 + ay * c2;
        acc.z = acc.z * c1 + az * c2; acc.w = acc.w * c1 + aw * c2;
        aea.x = aea.x * c1 + bx * c2; aea.y = aea.y * c1 + by * c2;
        aea.z = aea.z * c1 + bz * c2; aea.w = aea.w * c1 + bw * c2;
        m = mn;
    }

    // epilogue: e_contrib = aggEA @ We
    float4 e4 = make_float4(0.f, 0.f, 0.f, 0.f);
#pragma unroll
    for (int jg = 0; jg < 4; jg++) {
        int sl = (lane & 32) | (h * 4 + jg);
        float a0 = __shfl(aea.x, sl), a1 = __shfl(aea.y, sl);
        float a2 = __shfl(aea.z, sl), a3 = __shfl(aea.w, sl);
        float4 w0 = *(const float4*)(we_s + (jg * 4 + 0) * HC + pos * 4);
        float4 w1 = *(const float4*)(we_s + (jg * 4 + 1) * HC + pos * 4);
        float4 w2 = *(const float4*)(we_s + (jg * 4 + 2) * HC + pos * 4);
        float4 w3 = *(const float4*)(we_s + (jg * 4 + 3) * HC + pos * 4);
        e4.x += a0 * w0.x + a1 * w1.x + a2 * w2.x + a3 * w3.x;
        e4.y += a0 * w0.y + a1 * w1.y + a2 * w2.y + a3 * w3.y;
        e4.z += a0 * w0.z + a1 * w1.z + a2 * w2.z + a3 * w3.z;
        e4.w += a0 * w0.w + a1 * w1.w + a2 * w2.w + a3 * w3.w;
    }

    float inv = (rend > rbeg) ? 1.f / den : 0.f;
    float4 sk = ((const float4*)(Sf + (size_t)node * HC))[pos];
    float4 o = make_float4((acc.x + e4.x) * inv + sk.x, (acc.y + e4.y) * inv + sk.y,
                           (acc.z + e4.z) * inv + sk.z, (acc.w + e4.w) * inv + sk.w);
    float4 g4 = ((const float4*)bng)[pos];
    float4 b4 = ((const float4*)bnb)[pos];
    float4 m4 = ((const float4*)bnm)[pos];
    float4 vv4 = ((const float4*)bnv)[pos];
    o.x = fmaxf((o.x - m4.x) * rsqrtf(vv4.x + BN_EPS) * g4.x + b4.x, 0.f);
    o.y = fmaxf((o.y - m4.y) * rsqrtf(vv4.y + BN_EPS) * g4.y + b4.y, 0.f);
    o.z = fmaxf((o.z - m4.z) * rsqrtf(vv4.z + BN_EPS) * g4.z + b4.z, 0.f);
    o.w = fmaxf((o.w - m4.w) * rsqrtf(vv4.w + BN_EPS) * g4.w + b4.w, 0.f);
    if (sub == 0) ((float4*)(x_out + (size_t)node * HC))[pos] = o;
}

// ---------- fused mean-pool + MLP head ----------
__global__ __launch_bounds__(256) void pool_head(
    const float* __restrict__ x, const int* __restrict__ batch,
    const float* __restrict__ fc1_w, const float* __restrict__ fc1_b,
    const float* __restrict__ fc2_w, const float* __restrict__ fc2_b,
    float* __restrict__ out) {
    __shared__ float ps[4][HC];
    int q = threadIdx.x >> 6;
    int lane = threadIdx.x & 63;
    int g = blockIdx.x * 4 + q;
    int lo = 0, hi = N_NODES;
    while (lo < hi) { int mid = (lo + hi) >> 1; if (batch[mid] < g) lo = mid + 1; else hi = mid; }
    int beg = lo;
    lo = 0; hi = N_NODES;
    while (lo < hi) { int mid = (lo + hi) >> 1; if (batch[mid] < g + 1) lo = mid + 1; else hi = mid; }
    int end = lo;
    float s = 0.f;
    for (int i = beg; i < end; i++) s += x[(size_t)i * HC + lane];
    float inv = (end > beg) ? 1.f / (float)(end - beg) : 1.f;
    ps[q][lane] = s * inv;
    __syncthreads();
    float o = 0.f;
    if (lane < HID) {
        float a = fc1_b[lane];
#pragma unroll
        for (int i = 0; i < HC; i++) a = fmaf(ps[q][i], fc1_w[i * HID + lane], a);
        o = fmaxf(a, 0.f) * fc2_w[lane];
    }
    o += __shfl_xor(o, 1);
    o += __shfl_xor(o, 2);
    o += __shfl_xor(o, 4);
    o += __shfl_xor(o, 8);
    if (lane == 0) out[g] = o + fc2_b[0];
}

extern "C" void kernel_launch(void* const* d_in, const int* in_sizes, int n_in,
                              void* d_out, int out_size, void* d_ws, size_t ws_size,
                              hipStream_t stream) {
    const float* x         = (const float*)d_in[0];
    const int*   ei        = (const int*)d_in[1];
    const float* edge_attr = (const float*)d_in[2];
    const int*   batch     = (const int*)d_in[3];
    const float* Wq = (const float*)d_in[4];  const float* bq = (const float*)d_in[5];
    const float* Wk = (const float*)d_in[6];  const float* bk = (const float*)d_in[7];
    const float* Wv = (const float*)d_in[8];  const float* bv = (const float*)d_in[9];
    const float* We = (const float*)d_in[10];
    const float* Ws = (const float*)d_in[11]; const float* bs = (const float*)d_in[12];
    const float* bng = (const float*)d_in[13]; const float* bnb = (const float*)d_in[14];
    const float* bnm = (const float*)d_in[15]; const float* bnv = (const float*)d_in[16];
    const float* fc1_w = (const float*)d_in[17]; const float* fc1_b = (const float*)d_in[18];
    const float* fc2_w = (const float*)d_in[19]; const float* fc2_b = (const float*)d_in[20];
    float* out = (float*)d_out;

    char* wp = (char*)d_ws;
    auto alloc = [&](size_t b) { void* p = (void*)wp; wp += (b + 255) & ~(size_t)255; return p; };
    int*   deg     = (int*)alloc((size_t)N_NODES * 4);
    float* xA      = (float*)alloc((size_t)N_NODES * HC * 4);
    float* xB      = (float*)alloc((size_t)N_NODES * HC * 4);
    float* Qb      = (float*)alloc((size_t)N_NODES * HC * 4);
    float* Sb      = (float*)alloc((size_t)N_NODES * HC * 4);
    float* KV      = (float*)alloc((size_t)N_NODES * 2 * HC * 4);
    float* qweb    = (float*)alloc((size_t)N_NODES * HC * 4);
    int*   row_ptr = (int*)alloc((size_t)(N_NODES + 1) * 4);
    int*   nxt     = (int*)alloc((size_t)N_NODES * 4);
    int*   bsum    = (int*)alloc((size_t)256 * 4);
    int2*  ep_s    = (int2*)alloc((size_t)N_EDGES * 8);
    int*   src_s   = (int*)alloc((size_t)N_EDGES * 4);
    float* ea_s    = (float*)alloc((size_t)N_EDGES * EDIM * 4);

    (void)hipMemsetAsync(deg, 0, (size_t)N_NODES * 4, stream);

    // count_deg || qkvs layer 0 in one dispatch (independent inputs)
    count_qkvs0<<<CD_BLOCKS + QKVS_TILES, 256, 0, stream>>>(
        ei, deg, x, Wq, bq, Wk, bk, Wv, bv, Ws, bs, We, Qb, KV, Sb, qweb);
    scan1<<<SCAN_NBLK, 256, 0, stream>>>(deg, bsum);
    scan3<<<SCAN_NBLK, 256, 0, stream>>>(deg, bsum, row_ptr, nxt);
    scatter_eid<<<(N_EDGES + 255) / 256, 256, 0, stream>>>(ei, nxt, ep_s);
    permute_ea<<<(N_EDGES * 4 + 255) / 256, 256, 0, stream>>>(ep_s, edge_attr, ea_s, src_s);

    const float* xin = x;
    float* bufs[2] = {xA, xB};
    for (int l = 0; l < 3; l++) {
        float* xout = bufs[l & 1];
        if (l > 0) {
            qkvs_kernel<<<QKVS_TILES, 256, 0, stream>>>(
                xin, Wq + l * HC * HC, bq + l * HC, Wk + l * HC * HC, bk + l * HC,
                Wv + l * HC * HC, bv + l * HC, Ws + l * HC * HC, bs + l * HC,
                We + l * EDIM * HC, Qb, KV, Sb, qweb);
        }
        attn_kernel<<<N_NODES / 8, 256, 0, stream>>>(
            Qb, qweb, KV, Sb, row_ptr, src_s, ea_s, We + l * EDIM * HC,
            bng + l * HC, bnb + l * HC, bnm + l * HC, bnv + l * HC, xout);
        xin = xout;
    }
    pool_head<<<NGRAPH / 4, 256, 0, stream>>>(xin, batch, fc1_w, fc1_b, fc2_w, fc2_b, out);
}